// Round 7
// baseline (172.870 us; speedup 1.0000x reference)
//
#include <hip/hip_runtime.h>
#include <stdint.h>

typedef unsigned short ushort_t;
typedef __attribute__((ext_vector_type(8))) __bf16 bf16x8;
typedef __attribute__((ext_vector_type(8))) unsigned short ushortx8;
typedef __attribute__((ext_vector_type(4))) float floatx4;
typedef __attribute__((ext_vector_type(4))) unsigned int uint4v;

// ---------- helpers ----------
__device__ inline ushort_t f2bf(float f) {
  union { float f; unsigned u; } v; v.f = f;
  unsigned r = v.u + 0x7FFFu + ((v.u >> 16) & 1u);
  return (ushort_t)(r >> 16);
}

__device__ inline floatx4 mfma16(bf16x8 a, bf16x8 b, floatx4 c) {
  return __builtin_amdgcn_mfma_f32_16x16x32_bf16(a, b, c, 0, 0, 0);
}

__device__ inline void gload_lds16(const ushort_t* g, ushort_t* l) {
  __builtin_amdgcn_global_load_lds((__attribute__((address_space(1))) void*)(void*)(g),
                                   (__attribute__((address_space(3))) void*)(l),
                                   16, 0, 0);
}

// ---------- kernel 1: fused prep — x cast + both W transposes ----------
__global__ __launch_bounds__(256)
void k_prep(const float* __restrict__ x, ushort_t* __restrict__ xb,
            const float* __restrict__ Wqkv, ushort_t* __restrict__ wqkvT,
            const float* __restrict__ Wout, ushort_t* __restrict__ woutT) {
  int bx = blockIdx.x, tid = threadIdx.x;
  if (bx < 4096) {
    int i = (bx * 256 + tid) * 4;
    float4 v = *(const float4*)(x + i);
    ushort4 o;
    o.x = f2bf(v.x); o.y = f2bf(v.y); o.z = f2bf(v.z); o.w = f2bf(v.w);
    *(ushort4*)(xb + i) = o;
    return;
  }
  __shared__ float tile[32][33];
  const float* src; ushort_t* dst; int N, id;
  if (bx < 4096 + 768) { id = bx - 4096; src = Wqkv; dst = wqkvT; N = 1536; }
  else                 { id = bx - 4864; src = Wout; dst = woutT; N = 512;  }
  int k0 = (id & 15) * 32, n0 = (id >> 4) * 32;
  int c = tid & 31, r0 = tid >> 5;
#pragma unroll
  for (int i = 0; i < 4; ++i) {
    int r = r0 + i * 8;
    tile[r][c] = src[(size_t)(k0 + r) * N + n0 + c];
  }
  __syncthreads();
#pragma unroll
  for (int i = 0; i < 4; ++i) {
    int r = r0 + i * 8;
    dst[(size_t)(n0 + r) * 512 + k0 + c] = f2bf(tile[c][r]);
  }
}

// ---------- GEMM1: qkv = xb @ wqkvT^T, 128x128 tile, barrier-free K-loop ----------
// MFMA frags are contiguous 16B/lane in global: stream them straight to registers.
// LDS used only for the epilogue C-tile (store coalescing).
__global__ __launch_bounds__(256)
void k_gemm1(const ushort_t* __restrict__ A, const ushort_t* __restrict__ Bt,
             ushort_t* __restrict__ qd, ushort_t* __restrict__ kd,
             ushort_t* __restrict__ vtd) {
  __shared__ __align__(16) ushort_t smem[17408];   // epilogue C-tile 128x136
  const int tid = threadIdx.x;
  const int w = tid >> 6, l = tid & 63;
  const int lr = l & 15, lq = l >> 4;
  const int m0 = blockIdx.x * 128, n0 = blockIdx.y * 128;
  const int wm = w >> 1, wn = w & 1;

  const ushort_t* Ab = A + (size_t)(m0 + wm * 64 + lr) * 512 + lq * 8;
  const ushort_t* Bb = Bt + (size_t)(n0 + wn * 64 + lr) * 512 + lq * 8;

  floatx4 acc[4][4];
#pragma unroll
  for (int i = 0; i < 4; ++i)
#pragma unroll
    for (int j = 0; j < 4; ++j) acc[i][j] = (floatx4)0.0f;

#pragma unroll 2
  for (int k0 = 0; k0 < 512; k0 += 32) {
    bf16x8 af[4], bfr[4];
#pragma unroll
    for (int i = 0; i < 4; ++i) af[i] = *(const bf16x8*)(Ab + (size_t)i * 16 * 512 + k0);
#pragma unroll
    for (int j = 0; j < 4; ++j) bfr[j] = *(const bf16x8*)(Bb + (size_t)j * 16 * 512 + k0);
#pragma unroll
    for (int i = 0; i < 4; ++i)
#pragma unroll
      for (int j = 0; j < 4; ++j) acc[i][j] = mfma16(af[i], bfr[j], acc[i][j]);
  }

  if (blockIdx.y < 8) {
#pragma unroll
    for (int i = 0; i < 4; ++i)
#pragma unroll
      for (int j = 0; j < 4; ++j) {
        int col = wn * 64 + j * 16 + lr;
#pragma unroll
        for (int r = 0; r < 4; ++r) {
          int row = wm * 64 + i * 16 + lq * 4 + r;
          smem[row * 136 + col] = f2bf(acc[i][j][r]);
        }
      }
    __syncthreads();
#pragma unroll
    for (int p = 0; p < 8; ++p) {
      int row = p * 16 + (tid >> 4), c8 = (tid & 15) * 8;
      ushortx8 vv = *(const ushortx8*)&smem[row * 136 + c8];
      int n = n0 + c8;
      ushort_t* dst = (n >> 9) ? kd : qd;
      int h = (n >> 6) & 7, d = n & 63;
      int m = m0 + row, b = m >> 12, t = m & 4095;
      *(ushortx8*)&dst[(((size_t)(b * 8 + h)) * 4096 + t) * 64 + d] = vv;
    }
  } else {
#pragma unroll
    for (int i = 0; i < 4; ++i)
#pragma unroll
      for (int j = 0; j < 4; ++j) {
        int dcol = wn * 64 + j * 16 + lr;
        int trow = wm * 64 + i * 16 + lq * 4;
        ushort4 pv;
        pv.x = f2bf(acc[i][j][0]); pv.y = f2bf(acc[i][j][1]);
        pv.z = f2bf(acc[i][j][2]); pv.w = f2bf(acc[i][j][3]);
        *(ushort4*)&smem[dcol * 136 + trow] = pv;
      }
    __syncthreads();
#pragma unroll
    for (int p = 0; p < 8; ++p) {
      int row = p * 16 + (tid >> 4), c8 = (tid & 15) * 8;
      ushortx8 vv = *(const ushortx8*)&smem[row * 136 + c8];
      int n = n0 + row, h = (n >> 6) & 7, d = n & 63;
      int m = m0 + c8, b = m >> 12, t = m & 4095;
      *(ushortx8*)&vtd[(((size_t)(b * 8 + h)) * 64 + d) * 4096 + t] = vv;
    }
  }
}

// ---------- GEMM2: out = ao @ woutT^T + bias, 64x64 tile, barrier-free K-loop ----------
__global__ __launch_bounds__(256)
void k_gemm2(const ushort_t* __restrict__ A, const ushort_t* __restrict__ Bt,
             float* __restrict__ outf, const float* __restrict__ bias) {
  __shared__ __align__(16) float Cs[64 * 68];      // epilogue C-tile
  const int tid = threadIdx.x;
  const int w = tid >> 6, l = tid & 63;
  const int lr = l & 15, lq = l >> 4;
  const int m0 = blockIdx.x * 64, n0 = blockIdx.y * 64;
  const int wm = w >> 1, wn = w & 1;

  const ushort_t* Ab = A + (size_t)(m0 + wm * 32 + lr) * 512 + lq * 8;
  const ushort_t* Bb = Bt + (size_t)(n0 + wn * 32 + lr) * 512 + lq * 8;

  floatx4 acc[2][2];
#pragma unroll
  for (int i = 0; i < 2; ++i)
#pragma unroll
    for (int j = 0; j < 2; ++j) acc[i][j] = (floatx4)0.0f;

#pragma unroll 4
  for (int k0 = 0; k0 < 512; k0 += 32) {
    bf16x8 af[2], bfr[2];
#pragma unroll
    for (int i = 0; i < 2; ++i) af[i] = *(const bf16x8*)(Ab + (size_t)i * 16 * 512 + k0);
#pragma unroll
    for (int j = 0; j < 2; ++j) bfr[j] = *(const bf16x8*)(Bb + (size_t)j * 16 * 512 + k0);
#pragma unroll
    for (int i = 0; i < 2; ++i)
#pragma unroll
      for (int j = 0; j < 2; ++j) acc[i][j] = mfma16(af[i], bfr[j], acc[i][j]);
  }

#pragma unroll
  for (int i = 0; i < 2; ++i)
#pragma unroll
    for (int j = 0; j < 2; ++j) {
      int col = wn * 32 + j * 16 + lr;
      float bv = bias[n0 + col];
#pragma unroll
      for (int r = 0; r < 4; ++r) {
        int row = wm * 32 + i * 16 + lq * 4 + r;
        Cs[row * 68 + col] = acc[i][j][r] + bv;
      }
    }
  __syncthreads();
#pragma unroll
  for (int p = 0; p < 4; ++p) {
    int row = p * 16 + (tid >> 4), c = (tid & 15) * 4;
    float4 v0 = *(const float4*)&Cs[row * 68 + c];
    *(float4*)&outf[(size_t)(m0 + row) * 512 + n0 + c] = v0;
  }
}

// ---------- attention: K staged in LDS (bulk), V reuses buffer, O-tile coalesced ----------
// 1-D grid 1024 with XCD-locality remap: xcd = g&7 owns bh in {2*xcd, 2*xcd+1}.
__global__ __launch_bounds__(256)
void k_attn(const ushort_t* __restrict__ qa, const ushort_t* __restrict__ ka,
            const ushort_t* __restrict__ vta, ushort_t* __restrict__ ao) {
  __shared__ __align__(16) ushort_t S[20 * 1024];  // 40960 B: K, then V, then O-tile
  const int tid = threadIdx.x, w = tid >> 6, l = tid & 63;
  const int lr = l & 15, lq = l >> 4;
  const int g = blockIdx.x;
  const int xcd = g & 7, j = g >> 3;
  const int bh = xcd * 2 + (j & 1);
  const int qt0 = (j >> 1) * 64;
  const int qrow = qt0 + w * 16;

  const ushort_t* kbase = ka + (size_t)bh * 4096 * 64;
#pragma unroll
  for (int i = 0; i < 10; ++i) {
    int idx = w * 10 + i, blk = idx >> 1, half = idx & 1;
    int row = qt0 - 128 + blk * 16 + lr;
    row = min(max(row, 0), 4095);
    gload_lds16(kbase + (size_t)row * 64 + half * 32 + lq * 8, &S[blk * 1024 + half * 512]);
  }

  const ushort_t* qp = qa + ((size_t)bh * 4096 + qrow + lr) * 64 + lq * 8;
  bf16x8 qf0 = *(const bf16x8*)qp;
  bf16x8 qf1 = *(const bf16x8*)(qp + 32);

  __syncthreads();  // K staged

  const float Cc = 0.125f * 1.4426950408889634f;
  uint2 pk[18];
  pk[17].x = 0u; pk[17].y = 0u;
  float ps = 0.f;
#pragma unroll
  for (int kt = 0; kt < 17; ++kt) {
    const ushort_t* kp = &S[(w + kt) * 1024 + l * 8];
    bf16x8 kf0 = *(const bf16x8*)kp;
    bf16x8 kf1 = *(const bf16x8*)(kp + 512);
    floatx4 s = (floatx4)0.0f;
    s = mfma16(kf0, qf0, s);
    s = mfma16(kf1, qf1, s);
    float p[4];
#pragma unroll
    for (int r = 0; r < 4; ++r) {
      int r_rel = kt * 16 + lq * 4 + r;
      int kj = qrow - 128 + r_rel;
      bool ok = (kj >= 0) && (kj < 4096) && (r_rel >= lr) && (r_rel - lr <= 256);
      float e = ok ? exp2f(s[r] * Cc) : 0.f;
      ps += e;
      p[r] = e;
    }
    pk[kt].x = (unsigned)f2bf(p[0]) | ((unsigned)f2bf(p[1]) << 16);
    pk[kt].y = (unsigned)f2bf(p[2]) | ((unsigned)f2bf(p[3]) << 16);
  }

  ps += __shfl_xor(ps, 16, 64);
  ps += __shfl_xor(ps, 32, 64);
  float inv = __builtin_amdgcn_rcpf(ps);
  float invr[4];
#pragma unroll
  for (int r = 0; r < 4; ++r) invr[r] = __shfl(inv, lq * 4 + r, 64);

  __syncthreads();  // all waves done reading K from S

  const ushort_t* vbase = vta + (size_t)bh * 64 * 4096;
#pragma unroll
  for (int i = 0; i < 10; ++i) {
    int t = w * 10 + i, kt2 = t >> 2, nt = t & 3;
    int d = nt * 16 + lr;
    int key = qt0 - 128 + kt2 * 32 + lq * 8;
    key = min(max(key, 0), 4088);
    gload_lds16(vbase + (size_t)d * 4096 + key, &S[t * 512]);
  }

  const int srcA = ((l >> 4) & 1) * 32 + lr;
  const int srcB = srcA + 16;
  const bool selhi = (l & 32) != 0;
  bf16x8 pu9[9];
#pragma unroll
  for (int kk = 0; kk < 9; ++kk) {
    unsigned e0 = __shfl(pk[2 * kk].x, srcA, 64);
    unsigned e1 = __shfl(pk[2 * kk].y, srcA, 64);
    unsigned e2 = __shfl(pk[2 * kk].x, srcB, 64);
    unsigned e3 = __shfl(pk[2 * kk].y, srcB, 64);
    unsigned o0 = __shfl(pk[2 * kk + 1].x, srcA, 64);
    unsigned o1 = __shfl(pk[2 * kk + 1].y, srcA, 64);
    unsigned o2 = __shfl(pk[2 * kk + 1].x, srcB, 64);
    unsigned o3 = __shfl(pk[2 * kk + 1].y, srcB, 64);
    union { uint4v u; bf16x8 b; } pu;
    pu.u[0] = selhi ? o0 : e0;
    pu.u[1] = selhi ? o1 : e1;
    pu.u[2] = selhi ? o2 : e2;
    pu.u[3] = selhi ? o3 : e3;
    pu9[kk] = pu.b;
  }

  __syncthreads();  // V staged

  floatx4 oacc[4];
#pragma unroll
  for (int nt = 0; nt < 4; ++nt) oacc[nt] = (floatx4)0.0f;
#pragma unroll
  for (int kk = 0; kk < 9; ++kk) {
    int keyrel = w * 16 + kk * 32 + lq * 8;
    keyrel = min(keyrel, 312);
    int kt2 = keyrel >> 5, seg = (keyrel >> 3) & 3;
    const ushort_t* vsp = &S[kt2 * 2048 + seg * 128 + lr * 8];
#pragma unroll
    for (int nt = 0; nt < 4; ++nt) {
      bf16x8 vf = *(const bf16x8*)(vsp + nt * 512);
      oacc[nt] = mfma16(pu9[kk], vf, oacc[nt]);
    }
  }

  __syncthreads();  // all waves done reading V

#pragma unroll
  for (int nt = 0; nt < 4; ++nt)
#pragma unroll
    for (int r = 0; r < 4; ++r)
      S[(w * 16 + lq * 4 + r) * 72 + nt * 16 + lr] = f2bf(oacc[nt][r] * invr[r]);
  __syncthreads();

  int b = bh >> 3, h = bh & 7;
#pragma unroll
  for (int p = 0; p < 2; ++p) {
    int row = p * 32 + (tid >> 3), c8 = (tid & 7) * 8;
    ushortx8 vv = *(const ushortx8*)&S[row * 72 + c8];
    *(ushortx8*)&ao[((size_t)(b * 4096 + qt0 + row)) * 512 + h * 64 + c8] = vv;
  }
}

// ---------- launch ----------
extern "C" void kernel_launch(void* const* d_in, const int* in_sizes, int n_in,
                              void* d_out, int out_size, void* d_ws, size_t ws_size,
                              hipStream_t stream) {
  const float* x    = (const float*)d_in[0];
  const float* Wqkv = (const float*)d_in[1];
  const float* Wout = (const float*)d_in[2];
  const float* bout = (const float*)d_in[3];
  float* out = (float*)d_out;
  char* ws = (char*)d_ws;
  const size_t MB = 1024 * 1024;

  ushort_t* xb    = (ushort_t*)(ws);                 // 8 MB (reused as ao after gemm1)
  ushort_t* wqkvT = (ushort_t*)(ws + 8 * MB);        // 1.5 MB
  ushort_t* woutT = (ushort_t*)(ws + 9 * MB + MB/2); // 0.5 MB
  ushort_t* q     = (ushort_t*)(ws + 10 * MB);       // 8 MB
  ushort_t* k     = (ushort_t*)(ws + 18 * MB);       // 8 MB
  ushort_t* vt    = (ushort_t*)(ws + 26 * MB);       // 8 MB  (total 34 MB)
  ushort_t* ao    = xb;

  k_prep<<<5120, 256, 0, stream>>>(x, xb, Wqkv, wqkvT, Wout, woutT);
  k_gemm1<<<dim3(64, 12), 256, 0, stream>>>(xb, wqkvT, q, k, vt);
  k_attn<<<1024, 256, 0, stream>>>(q, k, vt, ao);
  k_gemm2<<<dim3(128, 8), 256, 0, stream>>>(ao, woutT, out, bout);
}

// Round 8
// 146.461 us; speedup vs baseline: 1.1803x; 1.1803x over previous
//
#include <hip/hip_runtime.h>
#include <stdint.h>

typedef unsigned short ushort_t;
typedef __attribute__((ext_vector_type(8))) __bf16 bf16x8;
typedef __attribute__((ext_vector_type(8))) unsigned short ushortx8;
typedef __attribute__((ext_vector_type(4))) float floatx4;
typedef __attribute__((ext_vector_type(4))) unsigned int uint4v;

// ---------- helpers ----------
__device__ inline ushort_t f2bf(float f) {
  union { float f; unsigned u; } v; v.f = f;
  unsigned r = v.u + 0x7FFFu + ((v.u >> 16) & 1u);
  return (ushort_t)(r >> 16);
}

__device__ inline floatx4 mfma16(bf16x8 a, bf16x8 b, floatx4 c) {
  return __builtin_amdgcn_mfma_f32_16x16x32_bf16(a, b, c, 0, 0, 0);
}

__device__ inline void gload_lds16(const ushort_t* g, ushort_t* l) {
  __builtin_amdgcn_global_load_lds((__attribute__((address_space(1))) void*)(void*)(g),
                                   (__attribute__((address_space(3))) void*)(l),
                                   16, 0, 0);
}

// ---------- kernel 1: fused prep — x cast + both W transposes ----------
__global__ __launch_bounds__(256)
void k_prep(const float* __restrict__ x, ushort_t* __restrict__ xb,
            const float* __restrict__ Wqkv, ushort_t* __restrict__ wqkvT,
            const float* __restrict__ Wout, ushort_t* __restrict__ woutT) {
  int bx = blockIdx.x, tid = threadIdx.x;
  if (bx < 4096) {
    int i = (bx * 256 + tid) * 4;
    float4 v = *(const float4*)(x + i);
    ushort4 o;
    o.x = f2bf(v.x); o.y = f2bf(v.y); o.z = f2bf(v.z); o.w = f2bf(v.w);
    *(ushort4*)(xb + i) = o;
    return;
  }
  __shared__ float tile[32][33];
  const float* src; ushort_t* dst; int N, id;
  if (bx < 4096 + 768) { id = bx - 4096; src = Wqkv; dst = wqkvT; N = 1536; }
  else                 { id = bx - 4864; src = Wout; dst = woutT; N = 512;  }
  int k0 = (id & 15) * 32, n0 = (id >> 4) * 32;
  int c = tid & 31, r0 = tid >> 5;
#pragma unroll
  for (int i = 0; i < 4; ++i) {
    int r = r0 + i * 8;
    tile[r][c] = src[(size_t)(k0 + r) * N + n0 + c];
  }
  __syncthreads();
#pragma unroll
  for (int i = 0; i < 4; ++i) {
    int r = r0 + i * 8;
    dst[(size_t)(n0 + r) * 512 + k0 + c] = f2bf(tile[c][r]);
  }
}

// ---------- GEMM1: qkv = xb @ wqkvT^T, 64x128 tile, BK=64, 6 blocks/CU ----------
// LDS-DMA staging (24 KB) -> high co-residency covers barrier drains.
// Epilogue through LDS C-tile: q/k coalesced 16B; v transposed -> vt coalesced 16B.
__global__ __launch_bounds__(256)
void k_gemm1(const ushort_t* __restrict__ A, const ushort_t* __restrict__ Bt,
             ushort_t* __restrict__ qd, ushort_t* __restrict__ kd,
             ushort_t* __restrict__ vtd) {
  __shared__ __align__(16) ushort_t smem[12288];   // 24 KB: staging A(4k)+B(8k); epi C-tile
  ushort_t* As = smem;           // 4096 shorts
  ushort_t* Bs = smem + 4096;    // 8192 shorts
  const int tid = threadIdx.x;
  const int w = tid >> 6, l = tid & 63;
  const int lr = l & 15, lq = l >> 4;
  const int m0 = blockIdx.x * 64, n0 = blockIdx.y * 128;
  const int wm = w >> 1, wn = w & 1;

  floatx4 acc[2][4];
#pragma unroll
  for (int i = 0; i < 2; ++i)
#pragma unroll
    for (int j = 0; j < 4; ++j) acc[i][j] = (floatx4)0.0f;

  for (int k0 = 0; k0 < 512; k0 += 64) {
#pragma unroll
    for (int i = 0; i < 6; ++i) {
      int idx = w * 6 + i;
      if (idx < 8) {
        int blk = idx >> 1, half = idx & 1;
        gload_lds16(A + (size_t)(m0 + blk * 16 + lr) * 512 + k0 + half * 32 + lq * 8,
                    &As[blk * 1024 + half * 512]);
      } else {
        int j = idx - 8, blk = j >> 1, half = j & 1;
        gload_lds16(Bt + (size_t)(n0 + blk * 16 + lr) * 512 + k0 + half * 32 + lq * 8,
                    &Bs[blk * 1024 + half * 512]);
      }
    }
    __syncthreads();
#pragma unroll
    for (int half = 0; half < 2; ++half) {
      bf16x8 af[2], bfr[4];
#pragma unroll
      for (int i = 0; i < 2; ++i)
        af[i] = *(const bf16x8*)&As[(wm * 2 + i) * 1024 + half * 512 + l * 8];
#pragma unroll
      for (int j = 0; j < 4; ++j)
        bfr[j] = *(const bf16x8*)&Bs[(wn * 4 + j) * 1024 + half * 512 + l * 8];
#pragma unroll
      for (int i = 0; i < 2; ++i)
#pragma unroll
        for (int j = 0; j < 4; ++j) acc[i][j] = mfma16(af[i], bfr[j], acc[i][j]);
    }
    __syncthreads();
  }

  if (blockIdx.y < 8) {
    // q/k: C-tile [t_rel][n_rel] 64x136
#pragma unroll
    for (int i = 0; i < 2; ++i)
#pragma unroll
      for (int j = 0; j < 4; ++j) {
        int col = wn * 64 + j * 16 + lr;
#pragma unroll
        for (int r = 0; r < 4; ++r) {
          int row = wm * 32 + i * 16 + lq * 4 + r;
          smem[row * 136 + col] = f2bf(acc[i][j][r]);
        }
      }
    __syncthreads();
#pragma unroll
    for (int p = 0; p < 4; ++p) {
      int row = p * 16 + (tid >> 4), c8 = (tid & 15) * 8;
      ushortx8 vv = *(const ushortx8*)&smem[row * 136 + c8];
      int n = n0 + c8;
      ushort_t* dst = (n >> 9) ? kd : qd;
      int h = (n >> 6) & 7, d = n & 63;
      int m = m0 + row, b = m >> 12, t = m & 4095;
      *(ushortx8*)&dst[(((size_t)(b * 8 + h)) * 4096 + t) * 64 + d] = vv;
    }
  } else {
    // v: transposed C-tile [n_rel(d)][t_rel] 128x72
#pragma unroll
    for (int i = 0; i < 2; ++i)
#pragma unroll
      for (int j = 0; j < 4; ++j) {
        int dcol = wn * 64 + j * 16 + lr;
        int trow = wm * 32 + i * 16 + lq * 4;
        ushort4 pv;
        pv.x = f2bf(acc[i][j][0]); pv.y = f2bf(acc[i][j][1]);
        pv.z = f2bf(acc[i][j][2]); pv.w = f2bf(acc[i][j][3]);
        *(ushort4*)&smem[dcol * 72 + trow] = pv;
      }
    __syncthreads();
#pragma unroll
    for (int p = 0; p < 4; ++p) {
      int row = p * 32 + (tid >> 3), c8 = (tid & 7) * 8;  // row = n_rel, c8 = t_rel
      ushortx8 vv = *(const ushortx8*)&smem[row * 72 + c8];
      int n = n0 + row, h = (n >> 6) & 7, d = n & 63;
      int m = m0 + c8, b = m >> 12, t = m & 4095;
      *(ushortx8*)&vtd[(((size_t)(b * 8 + h)) * 64 + d) * 4096 + t] = vv;
    }
  }
}

// ---------- GEMM2: out = ao @ woutT^T + bias, 64x128 tile, fp32 out ----------
__global__ __launch_bounds__(256)
void k_gemm2(const ushort_t* __restrict__ A, const ushort_t* __restrict__ Bt,
             float* __restrict__ outf, const float* __restrict__ bias) {
  __shared__ __align__(16) char smemc[33792];  // staging 24KB, then C-tile 64x132 fp32
  ushort_t* As = (ushort_t*)smemc;
  ushort_t* Bs = (ushort_t*)(smemc + 8192);
  float* Cs = (float*)smemc;
  const int tid = threadIdx.x;
  const int w = tid >> 6, l = tid & 63;
  const int lr = l & 15, lq = l >> 4;
  const int m0 = blockIdx.x * 64, n0 = blockIdx.y * 128;
  const int wm = w >> 1, wn = w & 1;

  floatx4 acc[2][4];
#pragma unroll
  for (int i = 0; i < 2; ++i)
#pragma unroll
    for (int j = 0; j < 4; ++j) acc[i][j] = (floatx4)0.0f;

  for (int k0 = 0; k0 < 512; k0 += 64) {
#pragma unroll
    for (int i = 0; i < 6; ++i) {
      int idx = w * 6 + i;
      if (idx < 8) {
        int blk = idx >> 1, half = idx & 1;
        gload_lds16(A + (size_t)(m0 + blk * 16 + lr) * 512 + k0 + half * 32 + lq * 8,
                    &As[blk * 1024 + half * 512]);
      } else {
        int j = idx - 8, blk = j >> 1, half = j & 1;
        gload_lds16(Bt + (size_t)(n0 + blk * 16 + lr) * 512 + k0 + half * 32 + lq * 8,
                    &Bs[blk * 1024 + half * 512]);
      }
    }
    __syncthreads();
#pragma unroll
    for (int half = 0; half < 2; ++half) {
      bf16x8 af[2], bfr[4];
#pragma unroll
      for (int i = 0; i < 2; ++i)
        af[i] = *(const bf16x8*)&As[(wm * 2 + i) * 1024 + half * 512 + l * 8];
#pragma unroll
      for (int j = 0; j < 4; ++j)
        bfr[j] = *(const bf16x8*)&Bs[(wn * 4 + j) * 1024 + half * 512 + l * 8];
#pragma unroll
      for (int i = 0; i < 2; ++i)
#pragma unroll
        for (int j = 0; j < 4; ++j) acc[i][j] = mfma16(af[i], bfr[j], acc[i][j]);
    }
    __syncthreads();
  }

#pragma unroll
  for (int i = 0; i < 2; ++i)
#pragma unroll
    for (int j = 0; j < 4; ++j) {
      int col = wn * 64 + j * 16 + lr;
      float bv = bias[n0 + col];
#pragma unroll
      for (int r = 0; r < 4; ++r) {
        int row = wm * 32 + i * 16 + lq * 4 + r;
        Cs[row * 132 + col] = acc[i][j][r] + bv;
      }
    }
  __syncthreads();
#pragma unroll
  for (int p = 0; p < 4; ++p) {
    int row = p * 16 + (tid >> 4), c = (tid & 15) * 8;
    float4 v0 = *(const float4*)&Cs[row * 132 + c];
    float4 v1 = *(const float4*)&Cs[row * 132 + c + 4];
    float* op = &outf[(size_t)(m0 + row) * 512 + n0 + c];
    *(float4*)op = v0;
    *(float4*)(op + 4) = v1;
  }
}

// ---------- attention: K staged in LDS (bulk), V reuses buffer, O-tile coalesced ----------
// 1-D grid 1024 with XCD-locality remap: xcd = g&7 owns bh in {2*xcd, 2*xcd+1}.
__global__ __launch_bounds__(256)
void k_attn(const ushort_t* __restrict__ qa, const ushort_t* __restrict__ ka,
            const ushort_t* __restrict__ vta, ushort_t* __restrict__ ao) {
  __shared__ __align__(16) ushort_t S[20 * 1024];  // 40960 B: K, then V, then O-tile
  const int tid = threadIdx.x, w = tid >> 6, l = tid & 63;
  const int lr = l & 15, lq = l >> 4;
  const int g = blockIdx.x;
  const int xcd = g & 7, j = g >> 3;
  const int bh = xcd * 2 + (j & 1);
  const int qt0 = (j >> 1) * 64;
  const int qrow = qt0 + w * 16;

  const ushort_t* kbase = ka + (size_t)bh * 4096 * 64;
#pragma unroll
  for (int i = 0; i < 10; ++i) {
    int idx = w * 10 + i, blk = idx >> 1, half = idx & 1;
    int row = qt0 - 128 + blk * 16 + lr;
    row = min(max(row, 0), 4095);
    gload_lds16(kbase + (size_t)row * 64 + half * 32 + lq * 8, &S[blk * 1024 + half * 512]);
  }

  const ushort_t* qp = qa + ((size_t)bh * 4096 + qrow + lr) * 64 + lq * 8;
  bf16x8 qf0 = *(const bf16x8*)qp;
  bf16x8 qf1 = *(const bf16x8*)(qp + 32);

  __syncthreads();  // K staged

  const float Cc = 0.125f * 1.4426950408889634f;
  uint2 pk[18];
  pk[17].x = 0u; pk[17].y = 0u;
  float ps = 0.f;
#pragma unroll
  for (int kt = 0; kt < 17; ++kt) {
    const ushort_t* kp = &S[(w + kt) * 1024 + l * 8];
    bf16x8 kf0 = *(const bf16x8*)kp;
    bf16x8 kf1 = *(const bf16x8*)(kp + 512);
    floatx4 s = (floatx4)0.0f;
    s = mfma16(kf0, qf0, s);
    s = mfma16(kf1, qf1, s);
    float p[4];
#pragma unroll
    for (int r = 0; r < 4; ++r) {
      int r_rel = kt * 16 + lq * 4 + r;
      int kj = qrow - 128 + r_rel;
      bool ok = (kj >= 0) && (kj < 4096) && (r_rel >= lr) && (r_rel - lr <= 256);
      float e = ok ? exp2f(s[r] * Cc) : 0.f;
      ps += e;
      p[r] = e;
    }
    pk[kt].x = (unsigned)f2bf(p[0]) | ((unsigned)f2bf(p[1]) << 16);
    pk[kt].y = (unsigned)f2bf(p[2]) | ((unsigned)f2bf(p[3]) << 16);
  }

  ps += __shfl_xor(ps, 16, 64);
  ps += __shfl_xor(ps, 32, 64);
  float inv = __builtin_amdgcn_rcpf(ps);
  float invr[4];
#pragma unroll
  for (int r = 0; r < 4; ++r) invr[r] = __shfl(inv, lq * 4 + r, 64);

  __syncthreads();  // all waves done reading K from S

  const ushort_t* vbase = vta + (size_t)bh * 64 * 4096;
#pragma unroll
  for (int i = 0; i < 10; ++i) {
    int t = w * 10 + i, kt2 = t >> 2, nt = t & 3;
    int d = nt * 16 + lr;
    int key = qt0 - 128 + kt2 * 32 + lq * 8;
    key = min(max(key, 0), 4088);
    gload_lds16(vbase + (size_t)d * 4096 + key, &S[t * 512]);
  }

  const int srcA = ((l >> 4) & 1) * 32 + lr;
  const int srcB = srcA + 16;
  const bool selhi = (l & 32) != 0;
  bf16x8 pu9[9];
#pragma unroll
  for (int kk = 0; kk < 9; ++kk) {
    unsigned e0 = __shfl(pk[2 * kk].x, srcA, 64);
    unsigned e1 = __shfl(pk[2 * kk].y, srcA, 64);
    unsigned e2 = __shfl(pk[2 * kk].x, srcB, 64);
    unsigned e3 = __shfl(pk[2 * kk].y, srcB, 64);
    unsigned o0 = __shfl(pk[2 * kk + 1].x, srcA, 64);
    unsigned o1 = __shfl(pk[2 * kk + 1].y, srcA, 64);
    unsigned o2 = __shfl(pk[2 * kk + 1].x, srcB, 64);
    unsigned o3 = __shfl(pk[2 * kk + 1].y, srcB, 64);
    union { uint4v u; bf16x8 b; } pu;
    pu.u[0] = selhi ? o0 : e0;
    pu.u[1] = selhi ? o1 : e1;
    pu.u[2] = selhi ? o2 : e2;
    pu.u[3] = selhi ? o3 : e3;
    pu9[kk] = pu.b;
  }

  __syncthreads();  // V staged

  floatx4 oacc[4];
#pragma unroll
  for (int nt = 0; nt < 4; ++nt) oacc[nt] = (floatx4)0.0f;
#pragma unroll
  for (int kk = 0; kk < 9; ++kk) {
    int keyrel = w * 16 + kk * 32 + lq * 8;
    keyrel = min(keyrel, 312);
    int kt2 = keyrel >> 5, seg = (keyrel >> 3) & 3;
    const ushort_t* vsp = &S[kt2 * 2048 + seg * 128 + lr * 8];
#pragma unroll
    for (int nt = 0; nt < 4; ++nt) {
      bf16x8 vf = *(const bf16x8*)(vsp + nt * 512);
      oacc[nt] = mfma16(pu9[kk], vf, oacc[nt]);
    }
  }

  __syncthreads();  // all waves done reading V

#pragma unroll
  for (int nt = 0; nt < 4; ++nt)
#pragma unroll
    for (int r = 0; r < 4; ++r)
      S[(w * 16 + lq * 4 + r) * 72 + nt * 16 + lr] = f2bf(oacc[nt][r] * invr[r]);
  __syncthreads();

  int b = bh >> 3, h = bh & 7;
#pragma unroll
  for (int p = 0; p < 2; ++p) {
    int row = p * 32 + (tid >> 3), c8 = (tid & 7) * 8;
    ushortx8 vv = *(const ushortx8*)&S[row * 72 + c8];
    *(ushortx8*)&ao[((size_t)(b * 4096 + qt0 + row)) * 512 + h * 64 + c8] = vv;
  }
}

// ---------- launch ----------
extern "C" void kernel_launch(void* const* d_in, const int* in_sizes, int n_in,
                              void* d_out, int out_size, void* d_ws, size_t ws_size,
                              hipStream_t stream) {
  const float* x    = (const float*)d_in[0];
  const float* Wqkv = (const float*)d_in[1];
  const float* Wout = (const float*)d_in[2];
  const float* bout = (const float*)d_in[3];
  float* out = (float*)d_out;
  char* ws = (char*)d_ws;
  const size_t MB = 1024 * 1024;

  ushort_t* xb    = (ushort_t*)(ws);                 // 8 MB (reused as ao after gemm1)
  ushort_t* wqkvT = (ushort_t*)(ws + 8 * MB);        // 1.5 MB
  ushort_t* woutT = (ushort_t*)(ws + 9 * MB + MB/2); // 0.5 MB
  ushort_t* q     = (ushort_t*)(ws + 10 * MB);       // 8 MB
  ushort_t* k     = (ushort_t*)(ws + 18 * MB);       // 8 MB
  ushort_t* vt    = (ushort_t*)(ws + 26 * MB);       // 8 MB  (total 34 MB)
  ushort_t* ao    = xb;

  k_prep<<<5120, 256, 0, stream>>>(x, xb, Wqkv, wqkvT, Wout, woutT);
  k_gemm1<<<dim3(128, 12), 256, 0, stream>>>(xb, wqkvT, q, k, vt);
  k_attn<<<1024, 256, 0, stream>>>(q, k, vt, ao);
  k_gemm2<<<dim3(128, 4), 256, 0, stream>>>(ao, woutT, out, bout);
}

// Round 9
// 144.452 us; speedup vs baseline: 1.1967x; 1.0139x over previous
//
#include <hip/hip_runtime.h>
#include <stdint.h>

typedef unsigned short ushort_t;
typedef __attribute__((ext_vector_type(8))) __bf16 bf16x8;
typedef __attribute__((ext_vector_type(8))) unsigned short ushortx8;
typedef __attribute__((ext_vector_type(4))) float floatx4;
typedef __attribute__((ext_vector_type(4))) unsigned int uint4v;

#define WAITCNT_VM(N) asm volatile("s_waitcnt vmcnt(" #N ")" ::: "memory")
#define BARRIER_RAW() asm volatile("s_barrier" ::: "memory")

// ---------- helpers ----------
__device__ inline ushort_t f2bf(float f) {
  union { float f; unsigned u; } v; v.f = f;
  unsigned r = v.u + 0x7FFFu + ((v.u >> 16) & 1u);
  return (ushort_t)(r >> 16);
}

__device__ inline floatx4 mfma16(bf16x8 a, bf16x8 b, floatx4 c) {
  return __builtin_amdgcn_mfma_f32_16x16x32_bf16(a, b, c, 0, 0, 0);
}

__device__ inline void gload_lds16(const ushort_t* g, ushort_t* l) {
  __builtin_amdgcn_global_load_lds((__attribute__((address_space(1))) void*)(void*)(g),
                                   (__attribute__((address_space(3))) void*)(l),
                                   16, 0, 0);
}

// ---------- kernel 1: fused prep — x cast + both W transposes ----------
__global__ __launch_bounds__(256)
void k_prep(const float* __restrict__ x, ushort_t* __restrict__ xb,
            const float* __restrict__ Wqkv, ushort_t* __restrict__ wqkvT,
            const float* __restrict__ Wout, ushort_t* __restrict__ woutT) {
  int bx = blockIdx.x, tid = threadIdx.x;
  if (bx < 4096) {
    int i = (bx * 256 + tid) * 4;
    float4 v = *(const float4*)(x + i);
    ushort4 o;
    o.x = f2bf(v.x); o.y = f2bf(v.y); o.z = f2bf(v.z); o.w = f2bf(v.w);
    *(ushort4*)(xb + i) = o;
    return;
  }
  __shared__ float tile[32][33];
  const float* src; ushort_t* dst; int N, id;
  if (bx < 4096 + 768) { id = bx - 4096; src = Wqkv; dst = wqkvT; N = 1536; }
  else                 { id = bx - 4864; src = Wout; dst = woutT; N = 512;  }
  int k0 = (id & 15) * 32, n0 = (id >> 4) * 32;
  int c = tid & 31, r0 = tid >> 5;
#pragma unroll
  for (int i = 0; i < 4; ++i) {
    int r = r0 + i * 8;
    tile[r][c] = src[(size_t)(k0 + r) * N + n0 + c];
  }
  __syncthreads();
#pragma unroll
  for (int i = 0; i < 4; ++i) {
    int r = r0 + i * 8;
    dst[(size_t)(n0 + r) * 512 + k0 + c] = f2bf(tile[c][r]);
  }
}

// ---------- shared staging: 64xK A rows + 128xK B rows, 24 DMAs (6/wave) ----------
__device__ inline void stage_ab(const ushort_t* __restrict__ A, const ushort_t* __restrict__ Bt,
                                ushort_t* buf, int m0, int n0, int k0,
                                int w, int lr, int lq) {
#pragma unroll
  for (int i = 0; i < 6; ++i) {
    int idx = w * 6 + i;
    if (idx < 8) {
      int blk = idx >> 1, half = idx & 1;
      gload_lds16(A + (size_t)(m0 + blk * 16 + lr) * 512 + k0 + half * 32 + lq * 8,
                  &buf[blk * 1024 + half * 512]);
    } else {
      int j = idx - 8, blk = j >> 1, half = j & 1;
      gload_lds16(Bt + (size_t)(n0 + blk * 16 + lr) * 512 + k0 + half * 32 + lq * 8,
                  &buf[4096 + blk * 1024 + half * 512]);
    }
  }
}

// ---------- GEMM1: qkv = xb @ wqkvT^T, 64x128 tile, dbuf-pipelined K-loop ----------
// vmcnt(6) + raw s_barrier: staging of set i+2 overlaps compute of set i+1.
__global__ __launch_bounds__(256)
void k_gemm1(const ushort_t* __restrict__ A, const ushort_t* __restrict__ Bt,
             ushort_t* __restrict__ qd, ushort_t* __restrict__ kd,
             ushort_t* __restrict__ vtd) {
  __shared__ __align__(16) ushort_t smem[24576];   // 48 KB: 2x(A 8KB + B 16KB); epi C-tile
  const int tid = threadIdx.x;
  const int w = tid >> 6, l = tid & 63;
  const int lr = l & 15, lq = l >> 4;
  const int m0 = blockIdx.x * 64, n0 = blockIdx.y * 128;
  const int wm = w >> 1, wn = w & 1;

  floatx4 acc[2][4];
#pragma unroll
  for (int i = 0; i < 2; ++i)
#pragma unroll
    for (int j = 0; j < 4; ++j) acc[i][j] = (floatx4)0.0f;

  stage_ab(A, Bt, smem,         m0, n0, 0,  w, lr, lq);
  stage_ab(A, Bt, smem + 12288, m0, n0, 64, w, lr, lq);

#pragma unroll
  for (int it = 0; it < 8; ++it) {
    if (it < 7) { WAITCNT_VM(6); } else { WAITCNT_VM(0); }
    BARRIER_RAW();
    const ushort_t* As = smem + (it & 1) * 12288;
    const ushort_t* Bs = As + 4096;
#pragma unroll
    for (int half = 0; half < 2; ++half) {
      bf16x8 af[2], bfr[4];
#pragma unroll
      for (int i = 0; i < 2; ++i)
        af[i] = *(const bf16x8*)&As[(wm * 2 + i) * 1024 + half * 512 + l * 8];
#pragma unroll
      for (int j = 0; j < 4; ++j)
        bfr[j] = *(const bf16x8*)&Bs[(wn * 4 + j) * 1024 + half * 512 + l * 8];
#pragma unroll
      for (int i = 0; i < 2; ++i)
#pragma unroll
        for (int j = 0; j < 4; ++j) acc[i][j] = mfma16(af[i], bfr[j], acc[i][j]);
    }
    BARRIER_RAW();
    if (it < 6)
      stage_ab(A, Bt, smem + (it & 1) * 12288, m0, n0, (it + 2) * 64, w, lr, lq);
  }
  __syncthreads();

  if (blockIdx.y < 8) {
    // q/k: C-tile [t_rel][n_rel] 64x136
#pragma unroll
    for (int i = 0; i < 2; ++i)
#pragma unroll
      for (int j = 0; j < 4; ++j) {
        int col = wn * 64 + j * 16 + lr;
#pragma unroll
        for (int r = 0; r < 4; ++r) {
          int row = wm * 32 + i * 16 + lq * 4 + r;
          smem[row * 136 + col] = f2bf(acc[i][j][r]);
        }
      }
    __syncthreads();
#pragma unroll
    for (int p = 0; p < 4; ++p) {
      int row = p * 16 + (tid >> 4), c8 = (tid & 15) * 8;
      ushortx8 vv = *(const ushortx8*)&smem[row * 136 + c8];
      int n = n0 + c8;
      ushort_t* dst = (n >> 9) ? kd : qd;
      int h = (n >> 6) & 7, d = n & 63;
      int m = m0 + row, b = m >> 12, t = m & 4095;
      *(ushortx8*)&dst[(((size_t)(b * 8 + h)) * 4096 + t) * 64 + d] = vv;
    }
  } else {
    // v: transposed C-tile [n_rel(d)][t_rel] 128x72
#pragma unroll
    for (int i = 0; i < 2; ++i)
#pragma unroll
      for (int j = 0; j < 4; ++j) {
        int dcol = wn * 64 + j * 16 + lr;
        int trow = wm * 32 + i * 16 + lq * 4;
        ushort4 pv;
        pv.x = f2bf(acc[i][j][0]); pv.y = f2bf(acc[i][j][1]);
        pv.z = f2bf(acc[i][j][2]); pv.w = f2bf(acc[i][j][3]);
        *(ushort4*)&smem[dcol * 72 + trow] = pv;
      }
    __syncthreads();
#pragma unroll
    for (int p = 0; p < 4; ++p) {
      int row = p * 32 + (tid >> 3), c8 = (tid & 7) * 8;  // row = n_rel, c8 = t_rel
      ushortx8 vv = *(const ushortx8*)&smem[row * 72 + c8];
      int n = n0 + row, h = (n >> 6) & 7, d = n & 63;
      int m = m0 + c8, b = m >> 12, t = m & 4095;
      *(ushortx8*)&vtd[(((size_t)(b * 8 + h)) * 64 + d) * 4096 + t] = vv;
    }
  }
}

// ---------- GEMM2: out = ao @ woutT^T + bias, 64x128 tile, dbuf-pipelined ----------
__global__ __launch_bounds__(256)
void k_gemm2(const ushort_t* __restrict__ A, const ushort_t* __restrict__ Bt,
             float* __restrict__ outf, const float* __restrict__ bias) {
  __shared__ __align__(16) char smemc[49152];  // 2x24KB staging; epi C-tile 64x132 fp32
  ushort_t* sm = (ushort_t*)smemc;
  float* Cs = (float*)smemc;
  const int tid = threadIdx.x;
  const int w = tid >> 6, l = tid & 63;
  const int lr = l & 15, lq = l >> 4;
  const int m0 = blockIdx.x * 64, n0 = blockIdx.y * 128;
  const int wm = w >> 1, wn = w & 1;

  floatx4 acc[2][4];
#pragma unroll
  for (int i = 0; i < 2; ++i)
#pragma unroll
    for (int j = 0; j < 4; ++j) acc[i][j] = (floatx4)0.0f;

  stage_ab(A, Bt, sm,         m0, n0, 0,  w, lr, lq);
  stage_ab(A, Bt, sm + 12288, m0, n0, 64, w, lr, lq);

#pragma unroll
  for (int it = 0; it < 8; ++it) {
    if (it < 7) { WAITCNT_VM(6); } else { WAITCNT_VM(0); }
    BARRIER_RAW();
    const ushort_t* As = sm + (it & 1) * 12288;
    const ushort_t* Bs = As + 4096;
#pragma unroll
    for (int half = 0; half < 2; ++half) {
      bf16x8 af[2], bfr[4];
#pragma unroll
      for (int i = 0; i < 2; ++i)
        af[i] = *(const bf16x8*)&As[(wm * 2 + i) * 1024 + half * 512 + l * 8];
#pragma unroll
      for (int j = 0; j < 4; ++j)
        bfr[j] = *(const bf16x8*)&Bs[(wn * 4 + j) * 1024 + half * 512 + l * 8];
#pragma unroll
      for (int i = 0; i < 2; ++i)
#pragma unroll
        for (int j = 0; j < 4; ++j) acc[i][j] = mfma16(af[i], bfr[j], acc[i][j]);
    }
    BARRIER_RAW();
    if (it < 6)
      stage_ab(A, Bt, sm + (it & 1) * 12288, m0, n0, (it + 2) * 64, w, lr, lq);
  }
  __syncthreads();

#pragma unroll
  for (int i = 0; i < 2; ++i)
#pragma unroll
    for (int j = 0; j < 4; ++j) {
      int col = wn * 64 + j * 16 + lr;
      float bv = bias[n0 + col];
#pragma unroll
      for (int r = 0; r < 4; ++r) {
        int row = wm * 32 + i * 16 + lq * 4 + r;
        Cs[row * 132 + col] = acc[i][j][r] + bv;
      }
    }
  __syncthreads();
#pragma unroll
  for (int p = 0; p < 4; ++p) {
    int row = p * 16 + (tid >> 4), c = (tid & 15) * 8;
    float4 v0 = *(const float4*)&Cs[row * 132 + c];
    float4 v1 = *(const float4*)&Cs[row * 132 + c + 4];
    float* op = &outf[(size_t)(m0 + row) * 512 + n0 + c];
    *(float4*)op = v0;
    *(float4*)(op + 4) = v1;
  }
}

// ---------- attention: K staged in LDS (bulk), V reuses buffer, O-tile coalesced ----------
// 1-D grid 1024 with XCD-locality remap: xcd = g&7 owns bh in {2*xcd, 2*xcd+1}.
__global__ __launch_bounds__(256)
void k_attn(const ushort_t* __restrict__ qa, const ushort_t* __restrict__ ka,
            const ushort_t* __restrict__ vta, ushort_t* __restrict__ ao) {
  __shared__ __align__(16) ushort_t S[20 * 1024];  // 40960 B: K, then V, then O-tile
  const int tid = threadIdx.x, w = tid >> 6, l = tid & 63;
  const int lr = l & 15, lq = l >> 4;
  const int g = blockIdx.x;
  const int xcd = g & 7, j = g >> 3;
  const int bh = xcd * 2 + (j & 1);
  const int qt0 = (j >> 1) * 64;
  const int qrow = qt0 + w * 16;

  const ushort_t* kbase = ka + (size_t)bh * 4096 * 64;
#pragma unroll
  for (int i = 0; i < 10; ++i) {
    int idx = w * 10 + i, blk = idx >> 1, half = idx & 1;
    int row = qt0 - 128 + blk * 16 + lr;
    row = min(max(row, 0), 4095);
    gload_lds16(kbase + (size_t)row * 64 + half * 32 + lq * 8, &S[blk * 1024 + half * 512]);
  }

  const ushort_t* qp = qa + ((size_t)bh * 4096 + qrow + lr) * 64 + lq * 8;
  bf16x8 qf0 = *(const bf16x8*)qp;
  bf16x8 qf1 = *(const bf16x8*)(qp + 32);

  __syncthreads();  // K staged

  const float Cc = 0.125f * 1.4426950408889634f;
  uint2 pk[18];
  pk[17].x = 0u; pk[17].y = 0u;
  float ps = 0.f;
#pragma unroll
  for (int kt = 0; kt < 17; ++kt) {
    const ushort_t* kp = &S[(w + kt) * 1024 + l * 8];
    bf16x8 kf0 = *(const bf16x8*)kp;
    bf16x8 kf1 = *(const bf16x8*)(kp + 512);
    floatx4 s = (floatx4)0.0f;
    s = mfma16(kf0, qf0, s);
    s = mfma16(kf1, qf1, s);
    float p[4];
#pragma unroll
    for (int r = 0; r < 4; ++r) {
      int r_rel = kt * 16 + lq * 4 + r;
      int kj = qrow - 128 + r_rel;
      bool ok = (kj >= 0) && (kj < 4096) && (r_rel >= lr) && (r_rel - lr <= 256);
      float e = ok ? exp2f(s[r] * Cc) : 0.f;
      ps += e;
      p[r] = e;
    }
    pk[kt].x = (unsigned)f2bf(p[0]) | ((unsigned)f2bf(p[1]) << 16);
    pk[kt].y = (unsigned)f2bf(p[2]) | ((unsigned)f2bf(p[3]) << 16);
  }

  ps += __shfl_xor(ps, 16, 64);
  ps += __shfl_xor(ps, 32, 64);
  float inv = __builtin_amdgcn_rcpf(ps);
  float invr[4];
#pragma unroll
  for (int r = 0; r < 4; ++r) invr[r] = __shfl(inv, lq * 4 + r, 64);

  __syncthreads();  // all waves done reading K from S

  const ushort_t* vbase = vta + (size_t)bh * 64 * 4096;
#pragma unroll
  for (int i = 0; i < 10; ++i) {
    int t = w * 10 + i, kt2 = t >> 2, nt = t & 3;
    int d = nt * 16 + lr;
    int key = qt0 - 128 + kt2 * 32 + lq * 8;
    key = min(max(key, 0), 4088);
    gload_lds16(vbase + (size_t)d * 4096 + key, &S[t * 512]);
  }

  const int srcA = ((l >> 4) & 1) * 32 + lr;
  const int srcB = srcA + 16;
  const bool selhi = (l & 32) != 0;
  bf16x8 pu9[9];
#pragma unroll
  for (int kk = 0; kk < 9; ++kk) {
    unsigned e0 = __shfl(pk[2 * kk].x, srcA, 64);
    unsigned e1 = __shfl(pk[2 * kk].y, srcA, 64);
    unsigned e2 = __shfl(pk[2 * kk].x, srcB, 64);
    unsigned e3 = __shfl(pk[2 * kk].y, srcB, 64);
    unsigned o0 = __shfl(pk[2 * kk + 1].x, srcA, 64);
    unsigned o1 = __shfl(pk[2 * kk + 1].y, srcA, 64);
    unsigned o2 = __shfl(pk[2 * kk + 1].x, srcB, 64);
    unsigned o3 = __shfl(pk[2 * kk + 1].y, srcB, 64);
    union { uint4v u; bf16x8 b; } pu;
    pu.u[0] = selhi ? o0 : e0;
    pu.u[1] = selhi ? o1 : e1;
    pu.u[2] = selhi ? o2 : e2;
    pu.u[3] = selhi ? o3 : e3;
    pu9[kk] = pu.b;
  }

  __syncthreads();  // V staged

  floatx4 oacc[4];
#pragma unroll
  for (int nt = 0; nt < 4; ++nt) oacc[nt] = (floatx4)0.0f;
#pragma unroll
  for (int kk = 0; kk < 9; ++kk) {
    int keyrel = w * 16 + kk * 32 + lq * 8;
    keyrel = min(keyrel, 312);
    int kt2 = keyrel >> 5, seg = (keyrel >> 3) & 3;
    const ushort_t* vsp = &S[kt2 * 2048 + seg * 128 + lr * 8];
#pragma unroll
    for (int nt = 0; nt < 4; ++nt) {
      bf16x8 vf = *(const bf16x8*)(vsp + nt * 512);
      oacc[nt] = mfma16(pu9[kk], vf, oacc[nt]);
    }
  }

  __syncthreads();  // all waves done reading V

#pragma unroll
  for (int nt = 0; nt < 4; ++nt)
#pragma unroll
    for (int r = 0; r < 4; ++r)
      S[(w * 16 + lq * 4 + r) * 72 + nt * 16 + lr] = f2bf(oacc[nt][r] * invr[r]);
  __syncthreads();

  int b = bh >> 3, h = bh & 7;
#pragma unroll
  for (int p = 0; p < 2; ++p) {
    int row = p * 32 + (tid >> 3), c8 = (tid & 7) * 8;
    ushortx8 vv = *(const ushortx8*)&S[row * 72 + c8];
    *(ushortx8*)&ao[((size_t)(b * 4096 + qt0 + row)) * 512 + h * 64 + c8] = vv;
  }
}

// ---------- launch ----------
extern "C" void kernel_launch(void* const* d_in, const int* in_sizes, int n_in,
                              void* d_out, int out_size, void* d_ws, size_t ws_size,
                              hipStream_t stream) {
  const float* x    = (const float*)d_in[0];
  const float* Wqkv = (const float*)d_in[1];
  const float* Wout = (const float*)d_in[2];
  const float* bout = (const float*)d_in[3];
  float* out = (float*)d_out;
  char* ws = (char*)d_ws;
  const size_t MB = 1024 * 1024;

  ushort_t* xb    = (ushort_t*)(ws);                 // 8 MB (reused as ao after gemm1)
  ushort_t* wqkvT = (ushort_t*)(ws + 8 * MB);        // 1.5 MB
  ushort_t* woutT = (ushort_t*)(ws + 9 * MB + MB/2); // 0.5 MB
  ushort_t* q     = (ushort_t*)(ws + 10 * MB);       // 8 MB
  ushort_t* k     = (ushort_t*)(ws + 18 * MB);       // 8 MB
  ushort_t* vt    = (ushort_t*)(ws + 26 * MB);       // 8 MB  (total 34 MB)
  ushort_t* ao    = xb;

  k_prep<<<5120, 256, 0, stream>>>(x, xb, Wqkv, wqkvT, Wout, woutT);
  k_gemm1<<<dim3(128, 12), 256, 0, stream>>>(xb, wqkvT, q, k, vt);
  k_attn<<<1024, 256, 0, stream>>>(q, k, vt, ao);
  k_gemm2<<<dim3(128, 4), 256, 0, stream>>>(ao, woutT, out, bout);
}

// Round 10
// 135.045 us; speedup vs baseline: 1.2801x; 1.0697x over previous
//
#include <hip/hip_runtime.h>
#include <stdint.h>

typedef unsigned short ushort_t;
typedef __attribute__((ext_vector_type(8))) __bf16 bf16x8;
typedef __attribute__((ext_vector_type(8))) unsigned short ushortx8;
typedef __attribute__((ext_vector_type(4))) float floatx4;
typedef __attribute__((ext_vector_type(4))) unsigned int uint4v;

#define BARRIER_RAW() asm volatile("s_barrier" ::: "memory")

// ---------- helpers ----------
__device__ inline ushort_t f2bf(float f) {
  union { float f; unsigned u; } v; v.f = f;
  unsigned r = v.u + 0x7FFFu + ((v.u >> 16) & 1u);
  return (ushort_t)(r >> 16);
}

__device__ inline floatx4 mfma16(bf16x8 a, bf16x8 b, floatx4 c) {
  return __builtin_amdgcn_mfma_f32_16x16x32_bf16(a, b, c, 0, 0, 0);
}

__device__ inline void gload_lds16(const ushort_t* g, ushort_t* l) {
  __builtin_amdgcn_global_load_lds((__attribute__((address_space(1))) void*)(void*)(g),
                                   (__attribute__((address_space(3))) void*)(l),
                                   16, 0, 0);
}

// ---------- kernel 1: fused prep — x cast + both W transposes ----------
__global__ __launch_bounds__(256)
void k_prep(const float* __restrict__ x, ushort_t* __restrict__ xb,
            const float* __restrict__ Wqkv, ushort_t* __restrict__ wqkvT,
            const float* __restrict__ Wout, ushort_t* __restrict__ woutT) {
  int bx = blockIdx.x, tid = threadIdx.x;
  if (bx < 4096) {
    int i = (bx * 256 + tid) * 4;
    float4 v = *(const float4*)(x + i);
    ushort4 o;
    o.x = f2bf(v.x); o.y = f2bf(v.y); o.z = f2bf(v.z); o.w = f2bf(v.w);
    *(ushort4*)(xb + i) = o;
    return;
  }
  __shared__ float tile[32][33];
  const float* src; ushort_t* dst; int N, id;
  if (bx < 4096 + 768) { id = bx - 4096; src = Wqkv; dst = wqkvT; N = 1536; }
  else                 { id = bx - 4864; src = Wout; dst = woutT; N = 512;  }
  int k0 = (id & 15) * 32, n0 = (id >> 4) * 32;
  int c = tid & 31, r0 = tid >> 5;
#pragma unroll
  for (int i = 0; i < 4; ++i) {
    int r = r0 + i * 8;
    tile[r][c] = src[(size_t)(k0 + r) * N + n0 + c];
  }
  __syncthreads();
#pragma unroll
  for (int i = 0; i < 4; ++i) {
    int r = r0 + i * 8;
    dst[(size_t)(n0 + r) * 512 + k0 + c] = f2bf(tile[c][r]);
  }
}

// ---------- GEMM1: qkv = xb @ wqkvT^T, 128x128 tile, BK=32 dbuf-pipelined ----------
// Min staged bytes (16 B/output) + vmcnt(4)/raw-barrier pipeline.
// Round r staged into buf r&1 (16 KB: A 8KB blocks 0..7, B 8KB blocks 0..7).
__global__ __launch_bounds__(256)
void k_gemm1(const ushort_t* __restrict__ A, const ushort_t* __restrict__ Bt,
             ushort_t* __restrict__ qd, ushort_t* __restrict__ kd,
             ushort_t* __restrict__ vtd) {
  __shared__ __align__(16) ushort_t smem[17408];   // 34816 B: 2x16KB staging / epi C-tile 128x136
  const int tid = threadIdx.x;
  const int w = tid >> 6, l = tid & 63;
  const int lr = l & 15, lq = l >> 4;
  const int m0 = blockIdx.x * 128, n0 = blockIdx.y * 128;
  const int wm = w >> 1, wn = w & 1;

  // stage one 32-k round into buf: 16 DMAs, 4 per wave
  auto stage = [&](int k0, int buf) {
#pragma unroll
    for (int i = 0; i < 4; ++i) {
      int idx = w * 4 + i;
      if (idx < 8)
        gload_lds16(A + (size_t)(m0 + idx * 16 + lr) * 512 + k0 + lq * 8,
                    &smem[buf * 8192 + idx * 512]);
      else
        gload_lds16(Bt + (size_t)(n0 + (idx - 8) * 16 + lr) * 512 + k0 + lq * 8,
                    &smem[buf * 8192 + 4096 + (idx - 8) * 512]);
    }
  };

  floatx4 acc[4][4];
#pragma unroll
  for (int i = 0; i < 4; ++i)
#pragma unroll
    for (int j = 0; j < 4; ++j) acc[i][j] = (floatx4)0.0f;

  stage(0, 0);
  stage(32, 1);

#pragma unroll
  for (int it = 0; it < 16; ++it) {
    if (it < 15) asm volatile("s_waitcnt vmcnt(4)" ::: "memory");
    else         asm volatile("s_waitcnt vmcnt(0)" ::: "memory");
    BARRIER_RAW();
    const ushort_t* As = &smem[(it & 1) * 8192];
    const ushort_t* Bs = As + 4096;
    bf16x8 af[4], bfr[4];
#pragma unroll
    for (int i = 0; i < 4; ++i) af[i] = *(const bf16x8*)&As[(wm * 4 + i) * 512 + l * 8];
#pragma unroll
    for (int j = 0; j < 4; ++j) bfr[j] = *(const bf16x8*)&Bs[(wn * 4 + j) * 512 + l * 8];
#pragma unroll
    for (int i = 0; i < 4; ++i)
#pragma unroll
      for (int j = 0; j < 4; ++j) acc[i][j] = mfma16(af[i], bfr[j], acc[i][j]);
    BARRIER_RAW();
    if (it < 14) stage((it + 2) * 32, it & 1);
  }
  __syncthreads();

  if (blockIdx.y < 8) {
    // q/k: C-tile [t_rel][n_rel], stride 136
#pragma unroll
    for (int i = 0; i < 4; ++i)
#pragma unroll
      for (int j = 0; j < 4; ++j) {
        int col = wn * 64 + j * 16 + lr;
#pragma unroll
        for (int r = 0; r < 4; ++r) {
          int row = wm * 64 + i * 16 + lq * 4 + r;
          smem[row * 136 + col] = f2bf(acc[i][j][r]);
        }
      }
    __syncthreads();
#pragma unroll
    for (int p = 0; p < 8; ++p) {
      int row = p * 16 + (tid >> 4), c8 = (tid & 15) * 8;
      ushortx8 vv = *(const ushortx8*)&smem[row * 136 + c8];
      int n = n0 + c8;
      ushort_t* dst = (n >> 9) ? kd : qd;
      int h = (n >> 6) & 7, d = n & 63;
      int m = m0 + row, b = m >> 12, t = m & 4095;
      *(ushortx8*)&dst[(((size_t)(b * 8 + h)) * 4096 + t) * 64 + d] = vv;
    }
  } else {
    // v: transposed C-tile [n_rel(d)][t_rel], stride 136
#pragma unroll
    for (int i = 0; i < 4; ++i)
#pragma unroll
      for (int j = 0; j < 4; ++j) {
        int dcol = wn * 64 + j * 16 + lr;
        int trow = wm * 64 + i * 16 + lq * 4;
        ushort4 pv;
        pv.x = f2bf(acc[i][j][0]); pv.y = f2bf(acc[i][j][1]);
        pv.z = f2bf(acc[i][j][2]); pv.w = f2bf(acc[i][j][3]);
        *(ushort4*)&smem[dcol * 136 + trow] = pv;
      }
    __syncthreads();
#pragma unroll
    for (int p = 0; p < 8; ++p) {
      int row = p * 16 + (tid >> 4), c8 = (tid & 15) * 8;
      ushortx8 vv = *(const ushortx8*)&smem[row * 136 + c8];
      int n = n0 + row, h = (n >> 6) & 7, d = n & 63;
      int m = m0 + c8, b = m >> 12, t = m & 4095;
      *(ushortx8*)&vtd[(((size_t)(b * 8 + h)) * 64 + d) * 4096 + t] = vv;
    }
  }
}

// ---------- staging for gemm2: 64xK A + 128xK B, 24 DMAs (6/wave) ----------
__device__ inline void stage_ab(const ushort_t* __restrict__ A, const ushort_t* __restrict__ Bt,
                                ushort_t* buf, int m0, int n0, int k0,
                                int w, int lr, int lq) {
#pragma unroll
  for (int i = 0; i < 6; ++i) {
    int idx = w * 6 + i;
    if (idx < 8) {
      int blk = idx >> 1, half = idx & 1;
      gload_lds16(A + (size_t)(m0 + blk * 16 + lr) * 512 + k0 + half * 32 + lq * 8,
                  &buf[blk * 1024 + half * 512]);
    } else {
      int j = idx - 8, blk = j >> 1, half = j & 1;
      gload_lds16(Bt + (size_t)(n0 + blk * 16 + lr) * 512 + k0 + half * 32 + lq * 8,
                  &buf[4096 + blk * 1024 + half * 512]);
    }
  }
}

// ---------- GEMM2: out = ao @ woutT^T + bias, 64x128 tile, dbuf-pipelined ----------
__global__ __launch_bounds__(256)
void k_gemm2(const ushort_t* __restrict__ A, const ushort_t* __restrict__ Bt,
             float* __restrict__ outf, const float* __restrict__ bias) {
  __shared__ __align__(16) char smemc[49152];  // 2x24KB staging; epi C-tile 64x132 fp32
  ushort_t* sm = (ushort_t*)smemc;
  float* Cs = (float*)smemc;
  const int tid = threadIdx.x;
  const int w = tid >> 6, l = tid & 63;
  const int lr = l & 15, lq = l >> 4;
  const int m0 = blockIdx.x * 64, n0 = blockIdx.y * 128;
  const int wm = w >> 1, wn = w & 1;

  floatx4 acc[2][4];
#pragma unroll
  for (int i = 0; i < 2; ++i)
#pragma unroll
    for (int j = 0; j < 4; ++j) acc[i][j] = (floatx4)0.0f;

  stage_ab(A, Bt, sm,         m0, n0, 0,  w, lr, lq);
  stage_ab(A, Bt, sm + 12288, m0, n0, 64, w, lr, lq);

#pragma unroll
  for (int it = 0; it < 8; ++it) {
    if (it < 7) asm volatile("s_waitcnt vmcnt(6)" ::: "memory");
    else        asm volatile("s_waitcnt vmcnt(0)" ::: "memory");
    BARRIER_RAW();
    const ushort_t* As = sm + (it & 1) * 12288;
    const ushort_t* Bs = As + 4096;
#pragma unroll
    for (int half = 0; half < 2; ++half) {
      bf16x8 af[2], bfr[4];
#pragma unroll
      for (int i = 0; i < 2; ++i)
        af[i] = *(const bf16x8*)&As[(wm * 2 + i) * 1024 + half * 512 + l * 8];
#pragma unroll
      for (int j = 0; j < 4; ++j)
        bfr[j] = *(const bf16x8*)&Bs[(wn * 4 + j) * 1024 + half * 512 + l * 8];
#pragma unroll
      for (int i = 0; i < 2; ++i)
#pragma unroll
        for (int j = 0; j < 4; ++j) acc[i][j] = mfma16(af[i], bfr[j], acc[i][j]);
    }
    BARRIER_RAW();
    if (it < 6)
      stage_ab(A, Bt, sm + (it & 1) * 12288, m0, n0, (it + 2) * 64, w, lr, lq);
  }
  __syncthreads();

#pragma unroll
  for (int i = 0; i < 2; ++i)
#pragma unroll
    for (int j = 0; j < 4; ++j) {
      int col = wn * 64 + j * 16 + lr;
      float bv = bias[n0 + col];
#pragma unroll
      for (int r = 0; r < 4; ++r) {
        int row = wm * 32 + i * 16 + lq * 4 + r;
        Cs[row * 132 + col] = acc[i][j][r] + bv;
      }
    }
  __syncthreads();
#pragma unroll
  for (int p = 0; p < 4; ++p) {
    int row = p * 16 + (tid >> 4), c = (tid & 15) * 8;
    float4 v0 = *(const float4*)&Cs[row * 132 + c];
    float4 v1 = *(const float4*)&Cs[row * 132 + c + 4];
    float* op = &outf[(size_t)(m0 + row) * 512 + n0 + c];
    *(float4*)op = v0;
    *(float4*)(op + 4) = v1;
  }
}

// ---------- attention: K staged in LDS (bulk), V reuses buffer, O-tile coalesced ----------
// 1-D grid 1024 with XCD-locality remap: xcd = g&7 owns bh in {2*xcd, 2*xcd+1}.
__global__ __launch_bounds__(256)
void k_attn(const ushort_t* __restrict__ qa, const ushort_t* __restrict__ ka,
            const ushort_t* __restrict__ vta, ushort_t* __restrict__ ao) {
  __shared__ __align__(16) ushort_t S[20 * 1024];  // 40960 B: K, then V, then O-tile
  const int tid = threadIdx.x, w = tid >> 6, l = tid & 63;
  const int lr = l & 15, lq = l >> 4;
  const int g = blockIdx.x;
  const int xcd = g & 7, j = g >> 3;
  const int bh = xcd * 2 + (j & 1);
  const int qt0 = (j >> 1) * 64;
  const int qrow = qt0 + w * 16;

  const ushort_t* kbase = ka + (size_t)bh * 4096 * 64;
#pragma unroll
  for (int i = 0; i < 10; ++i) {
    int idx = w * 10 + i, blk = idx >> 1, half = idx & 1;
    int row = qt0 - 128 + blk * 16 + lr;
    row = min(max(row, 0), 4095);
    gload_lds16(kbase + (size_t)row * 64 + half * 32 + lq * 8, &S[blk * 1024 + half * 512]);
  }

  const ushort_t* qp = qa + ((size_t)bh * 4096 + qrow + lr) * 64 + lq * 8;
  bf16x8 qf0 = *(const bf16x8*)qp;
  bf16x8 qf1 = *(const bf16x8*)(qp + 32);

  __syncthreads();  // K staged

  const float Cc = 0.125f * 1.4426950408889634f;
  uint2 pk[18];
  pk[17].x = 0u; pk[17].y = 0u;
  float ps = 0.f;
#pragma unroll
  for (int kt = 0; kt < 17; ++kt) {
    const ushort_t* kp = &S[(w + kt) * 1024 + l * 8];
    bf16x8 kf0 = *(const bf16x8*)kp;
    bf16x8 kf1 = *(const bf16x8*)(kp + 512);
    floatx4 s = (floatx4)0.0f;
    s = mfma16(kf0, qf0, s);
    s = mfma16(kf1, qf1, s);
    float p[4];
#pragma unroll
    for (int r = 0; r < 4; ++r) {
      int r_rel = kt * 16 + lq * 4 + r;
      int kj = qrow - 128 + r_rel;
      bool ok = (kj >= 0) && (kj < 4096) && (r_rel >= lr) && (r_rel - lr <= 256);
      float e = ok ? exp2f(s[r] * Cc) : 0.f;
      ps += e;
      p[r] = e;
    }
    pk[kt].x = (unsigned)f2bf(p[0]) | ((unsigned)f2bf(p[1]) << 16);
    pk[kt].y = (unsigned)f2bf(p[2]) | ((unsigned)f2bf(p[3]) << 16);
  }

  ps += __shfl_xor(ps, 16, 64);
  ps += __shfl_xor(ps, 32, 64);
  float inv = __builtin_amdgcn_rcpf(ps);
  float invr[4];
#pragma unroll
  for (int r = 0; r < 4; ++r) invr[r] = __shfl(inv, lq * 4 + r, 64);

  __syncthreads();  // all waves done reading K from S

  const ushort_t* vbase = vta + (size_t)bh * 64 * 4096;
#pragma unroll
  for (int i = 0; i < 10; ++i) {
    int t = w * 10 + i, kt2 = t >> 2, nt = t & 3;
    int d = nt * 16 + lr;
    int key = qt0 - 128 + kt2 * 32 + lq * 8;
    key = min(max(key, 0), 4088);
    gload_lds16(vbase + (size_t)d * 4096 + key, &S[t * 512]);
  }

  const int srcA = ((l >> 4) & 1) * 32 + lr;
  const int srcB = srcA + 16;
  const bool selhi = (l & 32) != 0;
  bf16x8 pu9[9];
#pragma unroll
  for (int kk = 0; kk < 9; ++kk) {
    unsigned e0 = __shfl(pk[2 * kk].x, srcA, 64);
    unsigned e1 = __shfl(pk[2 * kk].y, srcA, 64);
    unsigned e2 = __shfl(pk[2 * kk].x, srcB, 64);
    unsigned e3 = __shfl(pk[2 * kk].y, srcB, 64);
    unsigned o0 = __shfl(pk[2 * kk + 1].x, srcA, 64);
    unsigned o1 = __shfl(pk[2 * kk + 1].y, srcA, 64);
    unsigned o2 = __shfl(pk[2 * kk + 1].x, srcB, 64);
    unsigned o3 = __shfl(pk[2 * kk + 1].y, srcB, 64);
    union { uint4v u; bf16x8 b; } pu;
    pu.u[0] = selhi ? o0 : e0;
    pu.u[1] = selhi ? o1 : e1;
    pu.u[2] = selhi ? o2 : e2;
    pu.u[3] = selhi ? o3 : e3;
    pu9[kk] = pu.b;
  }

  __syncthreads();  // V staged

  floatx4 oacc[4];
#pragma unroll
  for (int nt = 0; nt < 4; ++nt) oacc[nt] = (floatx4)0.0f;
#pragma unroll
  for (int kk = 0; kk < 9; ++kk) {
    int keyrel = w * 16 + kk * 32 + lq * 8;
    keyrel = min(keyrel, 312);
    int kt2 = keyrel >> 5, seg = (keyrel >> 3) & 3;
    const ushort_t* vsp = &S[kt2 * 2048 + seg * 128 + lr * 8];
#pragma unroll
    for (int nt = 0; nt < 4; ++nt) {
      bf16x8 vf = *(const bf16x8*)(vsp + nt * 512);
      oacc[nt] = mfma16(pu9[kk], vf, oacc[nt]);
    }
  }

  __syncthreads();  // all waves done reading V

#pragma unroll
  for (int nt = 0; nt < 4; ++nt)
#pragma unroll
    for (int r = 0; r < 4; ++r)
      S[(w * 16 + lq * 4 + r) * 72 + nt * 16 + lr] = f2bf(oacc[nt][r] * invr[r]);
  __syncthreads();

  int b = bh >> 3, h = bh & 7;
#pragma unroll
  for (int p = 0; p < 2; ++p) {
    int row = p * 32 + (tid >> 3), c8 = (tid & 7) * 8;
    ushortx8 vv = *(const ushortx8*)&S[row * 72 + c8];
    *(ushortx8*)&ao[((size_t)(b * 4096 + qt0 + row)) * 512 + h * 64 + c8] = vv;
  }
}

// ---------- launch ----------
extern "C" void kernel_launch(void* const* d_in, const int* in_sizes, int n_in,
                              void* d_out, int out_size, void* d_ws, size_t ws_size,
                              hipStream_t stream) {
  const float* x    = (const float*)d_in[0];
  const float* Wqkv = (const float*)d_in[1];
  const float* Wout = (const float*)d_in[2];
  const float* bout = (const float*)d_in[3];
  float* out = (float*)d_out;
  char* ws = (char*)d_ws;
  const size_t MB = 1024 * 1024;

  ushort_t* xb    = (ushort_t*)(ws);                 // 8 MB (reused as ao after gemm1)
  ushort_t* wqkvT = (ushort_t*)(ws + 8 * MB);        // 1.5 MB
  ushort_t* woutT = (ushort_t*)(ws + 9 * MB + MB/2); // 0.5 MB
  ushort_t* q     = (ushort_t*)(ws + 10 * MB);       // 8 MB
  ushort_t* k     = (ushort_t*)(ws + 18 * MB);       // 8 MB
  ushort_t* vt    = (ushort_t*)(ws + 26 * MB);       // 8 MB  (total 34 MB)
  ushort_t* ao    = xb;

  k_prep<<<5120, 256, 0, stream>>>(x, xb, Wqkv, wqkvT, Wout, woutT);
  k_gemm1<<<dim3(64, 12), 256, 0, stream>>>(xb, wqkvT, q, k, vt);
  k_attn<<<1024, 256, 0, stream>>>(q, k, vt, ao);
  k_gemm2<<<dim3(128, 4), 256, 0, stream>>>(ao, woutT, out, bout);
}